// Round 3
// baseline (1183.787 us; speedup 1.0000x reference)
//
#include <hip/hip_runtime.h>
#include <math.h>

#define NVIEW 720
#define NDCT  1024
#define NZ    32
#define NX    512
#define NY    512

#define BX 16        // block tile x
#define BY 16        // block tile y
#define ZG 16        // z per block (z-split factor 2)
#define ZL 10        // z served from LDS stage
#define NR 24        // staged detector rows (16x16 tile spread <= 22, +slack)
#define RSTRIDE 12   // dwords per staged row (10 data + 2 pad; 48B, 16B-aligned)

typedef unsigned int uint;

// Round fp32 -> bf16 bits (RNE).
__device__ __forceinline__ uint f2bf_rne(float f) {
    uint u = __float_as_uint(f);
    return (u + 0x7fffu + ((u >> 16) & 1u)) >> 16;
}

// packed[v][i][z], z contiguous (32 dw per (v,i)).
// hi16 = dithered bf16(g0 = p[i])  (hi chosen so as_float(whole dword) ~= g0)
// lo16 = bf16(d = p[i+1]-p[i])     (exact bf16; consumer: d = as_float(u<<16))
// Input x: (Z=32, 1, NVIEW, NDCT); proj[v][z][i] = x[z][0][v][i].
// One wave per (v, 64-i block): coalesced reads, LDS stride-33 transpose
// (conflict-free), fully coalesced x4 writes.
__global__ __launch_bounds__(64) void pack_kernel(const float* __restrict__ x,
                                                  uint* __restrict__ packed) {
    __shared__ uint tr[64 * 33];             // [i_local][z], stride 33 -> bank-conflict-free
    const int l  = threadIdx.x;              // 0..63
    const int v  = blockIdx.x;               // 0..719
    const int ib = blockIdx.y * 64;          // i block base
    const bool last = (ib + 64 >= NDCT);
    const float* rowbase = x + (size_t)v * NDCT + ib;

    // Preload the "i = ib+64" boundary value for all 32 z into lanes 0..31.
    float pre = 0.0f;
    if (l < NZ && !last) pre = rowbase[(size_t)l * (NVIEW * NDCT) + 64];

    for (int z = 0; z < NZ; ++z) {
        const float* r = rowbase + (size_t)z * (NVIEW * NDCT);
        float a   = r[l];                    // coalesced 256B
        float a64 = __shfl(pre, z);
        float b   = __shfl(a, l + 1);
        if (l == 63) b = a64;                // neighbor across wave boundary
        uint lo = f2bf_rne(b - a);
        uint u  = (f2bf_rne(a) << 16) | lo;
        // Dither hi16 to cancel the lo-bit junk in as_float(u):
        uint up = u + 0x10000u, um = u - 0x10000u;
        float e0 = fabsf(__uint_as_float(u)  - a);
        float e1 = fabsf(__uint_as_float(up) - a);
        float e2 = fabsf(__uint_as_float(um) - a);
        if (e1 < e0) { u = up; e0 = e1; }    // NaN/sign-wrap candidates self-reject
        if (e2 < e0) { u = um; }
        tr[l * 33 + z] = u;                  // bank = (33l+z)%32 = (l+z)%32: conflict-free
    }
    __syncthreads();

    uint* obase = packed + ((size_t)v * NDCT + ib) * 32;
    #pragma unroll
    for (int it = 0; it < 8; ++it) {
        int c  = it * 64 + l;                // chunk 0..511; dst dword = 4c (coalesced)
        int il = c >> 3;
        int zc = (c & 7) * 4;
        uint4 w;
        w.x = tr[il * 33 + zc + 0];
        w.y = tr[il * 33 + zc + 1];
        w.z = tr[il * 33 + zc + 2];
        w.w = tr[il * 33 + zc + 3];
        *(uint4*)(obase + (size_t)c * 4) = w;
    }
}

// 3 VALU ops per sample:
//   acc += as_float(u)          (g0, junk pre-compensated at pack time)
//   acc  = fma(w, as_float(u<<16), acc)
#define SAMPLE(zz, uu) do { \
    acc[zz] += __uint_as_float(uu); \
    acc[zz]  = fmaf(w, __uint_as_float((uu) << 16), acc[zz]); \
} while (0)

// 16x16 pixel tile, z-group g in {0,1} (16 z each). ZL z from double-buffered
// LDS stage (one barrier/view, prefetch issued at loop top, consumed at loop
// bottom -> full view of flight time), 6 z direct from L1.
__global__ __launch_bounds__(256, 8) void bp_hybrid2(const uint* __restrict__ packed,
                                                     float* __restrict__ out) {
    __shared__ float2 cs[NVIEW];
    __shared__ int imintab[NVIEW];
    __shared__ __align__(16) uint stage[2][NR * RSTRIDE];   // 2 x 1152 B

    const int tid = threadIdx.y * BX + threadIdx.x;         // 0..255
    const int g   = blockIdx.z;                              // z-group
    const float xf0 = (float)(int)(blockIdx.x * BX) - 255.5f;
    const float yf0 = (float)(int)(blockIdx.y * BY) - 255.5f;

    // Per-view cos/sin + exact block-uniform floor(t_min) (same fmaf structure
    // as per-thread t; s>=0 so y-min at yf0; x-extreme corners cover c sign).
    for (int v = tid; v < NVIEW; v += BX * BY) {
        float th = (float)v * (float)(M_PI / NVIEW);
        float s, c;
        sincosf(th, &s, &c);
        cs[v] = make_float2(c, s);
        float b0 = fmaf(yf0, s, 511.5f);
        float b1 = fmaf(yf0 + (float)(BY - 1), s, 511.5f);
        float t00 = fmaf(xf0, c, b0);
        float t10 = fmaf(xf0 + (float)(BX - 1), c, b0);
        float t01 = fmaf(xf0, c, b1);
        float t11 = fmaf(xf0 + (float)(BX - 1), c, b1);
        imintab[v] = (int)fminf(fminf(t00, t10), fminf(t01, t11));
    }
    __syncthreads();

    const int x = blockIdx.x * BX + threadIdx.x;
    const int y = blockIdx.y * BY + threadIdx.y;
    const float xf = (float)x - 255.5f;
    const float yf = (float)y - 255.5f;

    float acc[ZG];
    #pragma unroll
    for (int z = 0; z < ZG; ++z) acc[z] = 0.0f;

    // Staging: NR*ZL = 240 dwords/view as 120 x2-slots; thread t<120.
    const bool sact = (tid < NR * (ZL / 2));
    const int  srow = tid / 5;
    const int  scol = (tid % 5) * 2;
    const size_t sg_off = ((size_t)srow << 5) + (g << 4) + scol;  // global dw offset within view/row-block
    const int  swr = srow * RSTRIDE + scol;                        // LDS dw offset

    uint2 st;
    if (sact) {  // prologue: stage view 0
        st = *(const uint2*)(packed + ((size_t)imintab[0] << 5) + sg_off);
        *(uint2*)&stage[0][swr] = st;
    }
    __syncthreads();

    for (int v = 0; v < NVIEW; ++v) {
        // [A] prefetch staging for v+1 (consumed at [F]; ~1 view of flight)
        if (sact && v + 1 < NVIEW) {
            st = *(const uint2*)(packed + ((size_t)(v + 1) << 15)
                                 + ((size_t)imintab[v + 1] << 5) + sg_off);
        }

        float2 a = cs[v];
        float t  = fmaf(xf, a.x, fmaf(yf, a.y, 511.5f));
        int   i0 = (int)t;                       // t in [150,873] -> trunc == floor
        float w  = t - (float)i0;
        int   rl = i0 - imintab[v];
        rl = max(0, min(rl, NR - 1));            // should never clamp (bound is exact)

        // [B] direct loads for z in [ZL,16) — issue early, consume last
        const uint* gp = packed + ((size_t)v << 15) + ((size_t)i0 << 5) + (g << 4) + ZL;
        uint2 q5 = *(const uint2*)(gp);          // z 10,11  (8B-aligned)
        uint4 q6 = *(const uint4*)(gp + 2);      // z 12..15 (16B-aligned)

        // [C] LDS reads: staged row rl (z 0..9)
        const uint* sp = &stage[v & 1][rl * RSTRIDE];
        uint4 qa = *(const uint4*)(sp);
        uint4 qb = *(const uint4*)(sp + 4);
        uint2 qc = *(const uint2*)(sp + 8);

        // [D] samples from LDS
        SAMPLE(0, qa.x); SAMPLE(1, qa.y); SAMPLE(2, qa.z); SAMPLE(3, qa.w);
        SAMPLE(4, qb.x); SAMPLE(5, qb.y); SAMPLE(6, qb.z); SAMPLE(7, qb.w);
        SAMPLE(8, qc.x); SAMPLE(9, qc.y);
        // [E] samples from direct path
        SAMPLE(10, q5.x); SAMPLE(11, q5.y);
        SAMPLE(12, q6.x); SAMPLE(13, q6.y); SAMPLE(14, q6.z); SAMPLE(15, q6.w);

        // [F] publish view v+1 stage (waits vmcnt on st only)
        if (sact && v + 1 < NVIEW) *(uint2*)&stage[(v + 1) & 1][swr] = st;
        // [G] one barrier per view
        __syncthreads();
    }

    const float scale = 0.0043633231299858236f;  // pi / 720
    #pragma unroll
    for (int lz = 0; lz < ZG; ++lz) {
        out[(((size_t)(g * ZG + lz)) * NY + y) * NX + x] = acc[lz] * scale;
    }
}

// Fallback (ws too small for packed array): direct fp32, two loads per sample.
__global__ __launch_bounds__(256) void bp_direct(const float* __restrict__ xin,
                                                 float* __restrict__ out) {
    __shared__ float2 cs[NVIEW];
    int lt = threadIdx.y * 64 + threadIdx.x;
    for (int v = lt; v < NVIEW; v += 256) {
        float th = (float)v * (float)(M_PI / NVIEW);
        float s, c;
        sincosf(th, &s, &c);
        cs[v] = make_float2(c, s);
    }
    __syncthreads();

    int x = blockIdx.x * 64 + threadIdx.x;
    int y = blockIdx.y * 4 + threadIdx.y;
    float xf = (float)x - 255.5f;
    float yf = (float)y - 255.5f;

    float acc[NZ];
    #pragma unroll
    for (int z = 0; z < NZ; ++z) acc[z] = 0.0f;

    for (int v = 0; v < NVIEW; ++v) {
        float2 a = cs[v];
        float t  = fmaf(xf, a.x, fmaf(yf, a.y, 511.5f));
        int   i0 = (int)t;
        float w  = t - (float)i0;
        const float* p = xin + (size_t)v * NDCT + i0;
        #pragma unroll
        for (int z = 0; z < NZ; ++z) {
            float g0 = p[(size_t)z * NVIEW * NDCT];
            float g1 = p[(size_t)z * NVIEW * NDCT + 1];
            acc[z] += fmaf(w, g1 - g0, g0);
        }
    }

    const float scale = 0.0043633231299858236f;
    #pragma unroll
    for (int z = 0; z < NZ; ++z) {
        out[((size_t)z * NY + y) * NX + x] = acc[z] * scale;
    }
}

extern "C" void kernel_launch(void* const* d_in, const int* in_sizes, int n_in,
                              void* d_out, int out_size, void* d_ws, size_t ws_size,
                              hipStream_t stream) {
    const float* x = (const float*)d_in[0];
    float* out = (float*)d_out;

    const size_t packed_bytes = (size_t)NVIEW * NDCT * NZ * sizeof(uint);  // 94.4 MB

    if (ws_size >= packed_bytes) {
        uint* packed = (uint*)d_ws;
        pack_kernel<<<dim3(NVIEW, NDCT / 64), 64, 0, stream>>>(x, packed);
        bp_hybrid2<<<dim3(NX / BX, NY / BY, 2), dim3(BX, BY), 0, stream>>>(packed, out);
    } else {
        bp_direct<<<dim3(NX / 64, NY / 4), dim3(64, 4), 0, stream>>>(x, out);
    }
}

// Round 4
// 837.768 us; speedup vs baseline: 1.4130x; 1.4130x over previous
//
#include <hip/hip_runtime.h>
#include <math.h>

#define NVIEW 720
#define NDCT  1024
#define NZ    32
#define NX    512
#define NY    512

#define BX 16        // block tile x
#define BY 16        // block tile y
#define ZG 16        // z per block (z-split factor 2)
#define NR 24        // staged detector rows (16x16 tile i0 spread <= 23)
#define RSTRIDE 20   // dwords per staged row (16 data + 4 pad; 80 B, 16B-aligned)

typedef unsigned int uint;

// Round fp32 -> bf16 bits (RNE).
__device__ __forceinline__ uint f2bf_rne(float f) {
    uint u = __float_as_uint(f);
    return (u + 0x7fffu + ((u >> 16) & 1u)) >> 16;
}

// packed[v][i][z], z contiguous (32 dw per (v,i)).
// hi16 = dithered bf16(g0 = p[i])  (hi chosen so as_float(whole dword) ~= g0)
// lo16 = bf16(d = p[i+1]-p[i])     (consumer: d = as_float(u<<16))
// Input x: (Z=32, 1, NVIEW, NDCT); proj[v][z][i] = x[z][0][v][i].
__global__ __launch_bounds__(64) void pack_kernel(const float* __restrict__ x,
                                                  uint* __restrict__ packed) {
    __shared__ uint tr[64 * 33];             // [i_local][z], stride 33 -> conflict-free
    const int l  = threadIdx.x;              // 0..63
    const int v  = blockIdx.x;               // 0..719
    const int ib = blockIdx.y * 64;          // i block base
    const bool last = (ib + 64 >= NDCT);
    const float* rowbase = x + (size_t)v * NDCT + ib;

    // Preload the "i = ib+64" boundary value for all 32 z into lanes 0..31.
    float pre = 0.0f;
    if (l < NZ && !last) pre = rowbase[(size_t)l * (NVIEW * NDCT) + 64];

    for (int z = 0; z < NZ; ++z) {
        const float* r = rowbase + (size_t)z * (NVIEW * NDCT);
        float a   = r[l];                    // coalesced 256B
        float a64 = __shfl(pre, z);
        float b   = __shfl(a, l + 1);
        if (l == 63) b = a64;                // neighbor across wave boundary
        uint lo = f2bf_rne(b - a);
        uint u  = (f2bf_rne(a) << 16) | lo;
        // Dither hi16 so as_float(u) is the best approx of a (cancels lo-bit junk):
        uint up = u + 0x10000u, um = u - 0x10000u;
        float e0 = fabsf(__uint_as_float(u)  - a);
        float e1 = fabsf(__uint_as_float(up) - a);
        float e2 = fabsf(__uint_as_float(um) - a);
        if (e1 < e0) { u = up; e0 = e1; }
        if (e2 < e0) { u = um; }
        tr[l * 33 + z] = u;
    }
    __syncthreads();

    uint* obase = packed + ((size_t)v * NDCT + ib) * 32;
    #pragma unroll
    for (int it = 0; it < 8; ++it) {
        int c  = it * 64 + l;                // chunk 0..511; dst dword = 4c (coalesced)
        int il = c >> 3;
        int zc = (c & 7) * 4;
        uint4 w;
        w.x = tr[il * 33 + zc + 0];
        w.y = tr[il * 33 + zc + 1];
        w.z = tr[il * 33 + zc + 2];
        w.w = tr[il * 33 + zc + 3];
        *(uint4*)(obase + (size_t)c * 4) = w;
    }
}

// 3 VALU ops per sample:
//   acc += as_float(u)          (g0; junk pre-compensated at pack time)
//   acc  = fma(w, as_float(u<<16), acc)
#define SAMPLE(zz, uu) do { \
    acc[zz] += __uint_as_float(uu); \
    acc[zz]  = fmaf(w, __uint_as_float((uu) << 16), acc[zz]); \
} while (0)

// 16x16 pixel tile, z-group g in {0,1} (16 z each). ALL z served from
// double-buffered LDS (gathers at LDS bank granularity; L1 sees only the
// coalesced staging loads). One barrier/view; prefetch at loop top, publish
// at loop bottom. XOR chunk swizzle -> provably conflict-free row gathers.
__global__ __launch_bounds__(256, 8) void bp_lds(const uint* __restrict__ packed,
                                                 float* __restrict__ out) {
    __shared__ float2 cs[NVIEW];
    __shared__ int imintab[NVIEW];
    __shared__ __align__(16) uint stage[2][NR * RSTRIDE];   // 2 x 1920 B

    const int tid = threadIdx.y * BX + threadIdx.x;         // 0..255
    const int g   = blockIdx.z;                              // z-group
    const float xf0 = (float)(int)(blockIdx.x * BX) - 255.5f;
    const float yf0 = (float)(int)(blockIdx.y * BY) - 255.5f;

    // Per-view cos/sin + exact block-uniform floor(t_min) (same fmaf structure
    // as the per-thread t; fmaf monotone per-operand; corners cover extremes).
    for (int v = tid; v < NVIEW; v += BX * BY) {
        float th = (float)v * (float)(M_PI / NVIEW);
        float s, c;
        sincosf(th, &s, &c);
        cs[v] = make_float2(c, s);
        float b0 = fmaf(yf0, s, 511.5f);
        float b1 = fmaf(yf0 + (float)(BY - 1), s, 511.5f);
        float t00 = fmaf(xf0, c, b0);
        float t10 = fmaf(xf0 + (float)(BX - 1), c, b0);
        float t01 = fmaf(xf0, c, b1);
        float t11 = fmaf(xf0 + (float)(BX - 1), c, b1);
        imintab[v] = (int)fminf(fminf(t00, t10), fminf(t01, t11));
    }
    __syncthreads();

    const int x = blockIdx.x * BX + threadIdx.x;
    const int y = blockIdx.y * BY + threadIdx.y;
    const float xf = (float)x - 255.5f;
    const float yf = (float)y - 255.5f;

    float acc[ZG];
    #pragma unroll
    for (int z = 0; z < ZG; ++z) acc[z] = 0.0f;

    // Staging: NR rows x 16 dw = 96 x4-chunks, spread over all 4 waves
    // (24 lanes per wave) so barrier arrival stays balanced.
    const int  wv   = tid >> 6;
    const int  ln   = tid & 63;
    const bool sact = (ln < 24);
    const int  slot = wv * 24 + ln;          // 0..95
    const int  sr   = slot >> 2;             // staged row 0..23
    const int  sch  = slot & 3;              // logical 16B chunk 0..3
    const size_t sg_off = ((size_t)sr << 5) + (g << 4) + (sch << 2);       // global dw off
    const int  swr  = sr * RSTRIDE + (((sch ^ (sr >> 3)) & 3) << 2);       // swizzled LDS dw

    uint4 st;
    if (sact) {  // prologue: stage view 0 into buffer 0
        st = *(const uint4*)(packed + ((size_t)imintab[0] << 5) + sg_off);
        *(uint4*)&stage[0][swr] = st;
    }
    __syncthreads();

    for (int v = 0; v < NVIEW; ++v) {
        // [A] prefetch staging for v+1 (consumed at [F]; ~1 view of flight time)
        if (sact && v + 1 < NVIEW) {
            st = *(const uint4*)(packed + ((size_t)(v + 1) << 15)
                                 + ((size_t)imintab[v + 1] << 5) + sg_off);
        }

        float2 a = cs[v];
        float t  = fmaf(xf, a.x, fmaf(yf, a.y, 511.5f));
        int   i0 = (int)t;                       // t in [150,873] -> trunc == floor
        float w  = t - (float)i0;
        int   rl = i0 - imintab[v];
        rl = max(0, min(rl, NR - 1));            // guard; bound is exact

        // [C] LDS gather: 4x b128, XOR-swizzled chunks (conflict-free)
        const uint* sp = stage[v & 1] + rl * RSTRIDE;
        const int rot = rl >> 3;                 // 0..2
        uint4 q0 = *(const uint4*)(sp + (((0 ^ rot) & 3) << 2));
        uint4 q1 = *(const uint4*)(sp + (((1 ^ rot) & 3) << 2));
        uint4 q2 = *(const uint4*)(sp + (((2 ^ rot) & 3) << 2));
        uint4 q3 = *(const uint4*)(sp + (((3 ^ rot) & 3) << 2));

        SAMPLE( 0, q0.x); SAMPLE( 1, q0.y); SAMPLE( 2, q0.z); SAMPLE( 3, q0.w);
        SAMPLE( 4, q1.x); SAMPLE( 5, q1.y); SAMPLE( 6, q1.z); SAMPLE( 7, q1.w);
        SAMPLE( 8, q2.x); SAMPLE( 9, q2.y); SAMPLE(10, q2.z); SAMPLE(11, q2.w);
        SAMPLE(12, q3.x); SAMPLE(13, q3.y); SAMPLE(14, q3.z); SAMPLE(15, q3.w);

        // [F] publish view v+1 stage (vmcnt waits only on st, issued at [A])
        if (sact && v + 1 < NVIEW) *(uint4*)&stage[(v + 1) & 1][swr] = st;
        // [G] one barrier per view (write of buf B in iter v+1 is ordered
        // after all iter-v reads of B by this barrier -> race-free dbuf)
        __syncthreads();
    }

    const float scale = 0.0043633231299858236f;  // pi / 720
    #pragma unroll
    for (int lz = 0; lz < ZG; ++lz) {
        out[(((size_t)(g * ZG + lz)) * NY + y) * NX + x] = acc[lz] * scale;
    }
}

// Fallback (ws too small for packed array): direct fp32, two loads per sample.
__global__ __launch_bounds__(256) void bp_direct(const float* __restrict__ xin,
                                                 float* __restrict__ out) {
    __shared__ float2 cs[NVIEW];
    int lt = threadIdx.y * 64 + threadIdx.x;
    for (int v = lt; v < NVIEW; v += 256) {
        float th = (float)v * (float)(M_PI / NVIEW);
        float s, c;
        sincosf(th, &s, &c);
        cs[v] = make_float2(c, s);
    }
    __syncthreads();

    int x = blockIdx.x * 64 + threadIdx.x;
    int y = blockIdx.y * 4 + threadIdx.y;
    float xf = (float)x - 255.5f;
    float yf = (float)y - 255.5f;

    float acc[NZ];
    #pragma unroll
    for (int z = 0; z < NZ; ++z) acc[z] = 0.0f;

    for (int v = 0; v < NVIEW; ++v) {
        float2 a = cs[v];
        float t  = fmaf(xf, a.x, fmaf(yf, a.y, 511.5f));
        int   i0 = (int)t;
        float w  = t - (float)i0;
        const float* p = xin + (size_t)v * NDCT + i0;
        #pragma unroll
        for (int z = 0; z < NZ; ++z) {
            float g0 = p[(size_t)z * NVIEW * NDCT];
            float g1 = p[(size_t)z * NVIEW * NDCT + 1];
            acc[z] += fmaf(w, g1 - g0, g0);
        }
    }

    const float scale = 0.0043633231299858236f;
    #pragma unroll
    for (int z = 0; z < NZ; ++z) {
        out[((size_t)z * NY + y) * NX + x] = acc[z] * scale;
    }
}

extern "C" void kernel_launch(void* const* d_in, const int* in_sizes, int n_in,
                              void* d_out, int out_size, void* d_ws, size_t ws_size,
                              hipStream_t stream) {
    const float* x = (const float*)d_in[0];
    float* out = (float*)d_out;

    const size_t packed_bytes = (size_t)NVIEW * NDCT * NZ * sizeof(uint);  // 94.4 MB

    if (ws_size >= packed_bytes) {
        uint* packed = (uint*)d_ws;
        pack_kernel<<<dim3(NVIEW, NDCT / 64), 64, 0, stream>>>(x, packed);
        bp_lds<<<dim3(NX / BX, NY / BY, 2), dim3(BX, BY), 0, stream>>>(packed, out);
    } else {
        bp_direct<<<dim3(NX / 64, NY / 4), dim3(64, 4), 0, stream>>>(x, out);
    }
}

// Round 5
// 672.490 us; speedup vs baseline: 1.7603x; 1.2458x over previous
//
#include <hip/hip_runtime.h>
#include <math.h>

#define NVIEW 720
#define NDCT  1024
#define NZ    32
#define NX    512
#define NY    512

#define BX 16        // block tile x
#define BY 16        // block tile y
#define ZG 16        // z per block (z-split factor 2)
#define NR 24        // staged detector rows (16x16 tile i0 spread <= 23)
#define RSTRIDE 20   // dwords per staged row (16 data + 4 pad; 80 B).
                     // Bank-group of chunk c in row r = (5r + c) mod 8, injective in
                     // r mod 8 -> only dr in {8,16} alias; measured free (R1: 0 conflicts).
                     // Do NOT swizzle chunks: R3's XOR swizzle created dr=3,7 pileups (8.2e7).

typedef unsigned int uint;

#if __has_builtin(__builtin_amdgcn_fdot2)
#define USE_FDOT2 1
typedef _Float16 half2v __attribute__((ext_vector_type(2)));
#else
#define USE_FDOT2 0
#endif

// Round fp32 -> bf16 bits (RNE).
__device__ __forceinline__ uint f2bf_rne(float f) {
    uint u = __float_as_uint(f);
    return (u + 0x7fffu + ((u >> 16) & 1u)) >> 16;
}

// Packed word for (v, i, z):
//  fdot2 path:  lo16 = f16(g0 = p[i]), hi16 = f16(d = p[i+1]-p[i])
//               consumer: acc = v_dot2_f32_f16(word, {1.0, w}, acc)  -- 1 VALU/sample
//  fallback:    hi16 = dithered bf16(g0), lo16 = bf16(d)             -- 3 VALU/sample
__device__ __forceinline__ uint pack_word(float a, float b) {
#if USE_FDOT2
    union { _Float16 h[2]; uint u; } r;
    r.h[0] = (_Float16)a;         // g0 in low half
    r.h[1] = (_Float16)(b - a);   // d  in high half
    return r.u;
#else
    uint lo = f2bf_rne(b - a);
    uint u  = (f2bf_rne(a) << 16) | lo;
    uint up = u + 0x10000u, um = u - 0x10000u;
    float e0 = fabsf(__uint_as_float(u)  - a);
    float e1 = fabsf(__uint_as_float(up) - a);
    float e2 = fabsf(__uint_as_float(um) - a);
    if (e1 < e0) { u = up; e0 = e1; }
    if (e2 < e0) { u = um; }
    return u;
#endif
}

// packed[v][i][z], z contiguous (32 dw per (v,i)).
// Input x: (Z=32, 1, NVIEW, NDCT); proj[v][z][i] = x[z][0][v][i].
// One wave per (v, 64-i block): coalesced reads, LDS stride-33 transpose
// (conflict-free), fully coalesced x4 writes.
__global__ __launch_bounds__(64) void pack_kernel(const float* __restrict__ x,
                                                  uint* __restrict__ packed) {
    __shared__ uint tr[64 * 33];             // [i_local][z], stride 33 -> conflict-free
    const int l  = threadIdx.x;              // 0..63
    const int v  = blockIdx.x;               // 0..719
    const int ib = blockIdx.y * 64;          // i block base
    const bool last = (ib + 64 >= NDCT);
    const float* rowbase = x + (size_t)v * NDCT + ib;

    // Preload the "i = ib+64" boundary value for all 32 z into lanes 0..31.
    float pre = 0.0f;
    if (l < NZ && !last) pre = rowbase[(size_t)l * (NVIEW * NDCT) + 64];

    for (int z = 0; z < NZ; ++z) {
        const float* r = rowbase + (size_t)z * (NVIEW * NDCT);
        float a   = r[l];                    // coalesced 256B
        float a64 = __shfl(pre, z);
        float b   = __shfl(a, l + 1);
        if (l == 63) b = a64;                // neighbor across wave boundary
        tr[l * 33 + z] = pack_word(a, b);
    }
    __syncthreads();

    uint* obase = packed + ((size_t)v * NDCT + ib) * 32;
    #pragma unroll
    for (int it = 0; it < 8; ++it) {
        int c  = it * 64 + l;                // chunk 0..511; dst dword = 4c (coalesced)
        int il = c >> 3;
        int zc = (c & 7) * 4;
        uint4 w4;
        w4.x = tr[il * 33 + zc + 0];
        w4.y = tr[il * 33 + zc + 1];
        w4.z = tr[il * 33 + zc + 2];
        w4.w = tr[il * 33 + zc + 3];
        *(uint4*)(obase + (size_t)c * 4) = w4;
    }
}

#if USE_FDOT2
// 1 VALU op per sample: acc = g0*1 + d*w + acc  (products in f32)
#define SAMPLE(zz, uu) do { \
    union { uint q; half2v h; } _c; _c.q = (uu); \
    acc[zz] = __builtin_amdgcn_fdot2(_c.h, wpair, acc[zz], false); \
} while (0)
#else
// 3 VALU ops per sample (bf16 fallback).
#define SAMPLE(zz, uu) do { \
    acc[zz] += __uint_as_float(uu); \
    acc[zz]  = fmaf(w, __uint_as_float((uu) << 16), acc[zz]); \
} while (0)
#endif

// 16x16 pixel tile, z-group g in {0,1} (16 z each). ALL z served from
// double-buffered LDS. One barrier/view; prefetch at loop top, publish at
// loop bottom (staging load gets a full view of flight time).
__global__ __launch_bounds__(256, 8) void bp_lds(const uint* __restrict__ packed,
                                                 float* __restrict__ out) {
    __shared__ float2 cs[NVIEW];
    __shared__ int imintab[NVIEW];
    __shared__ __align__(16) uint stage[2][NR * RSTRIDE];   // 2 x 1920 B

    const int tid = threadIdx.y * BX + threadIdx.x;         // 0..255
    const int g   = blockIdx.z;                              // z-group
    const float xf0 = (float)(int)(blockIdx.x * BX) - 255.5f;
    const float yf0 = (float)(int)(blockIdx.y * BY) - 255.5f;

    // Per-view cos/sin + exact block-uniform floor(t_min) (same fmaf structure
    // as the per-thread t; fmaf monotone per-operand; corners cover extremes).
    for (int v = tid; v < NVIEW; v += BX * BY) {
        float th = (float)v * (float)(M_PI / NVIEW);
        float s, c;
        sincosf(th, &s, &c);
        cs[v] = make_float2(c, s);
        float b0 = fmaf(yf0, s, 511.5f);
        float b1 = fmaf(yf0 + (float)(BY - 1), s, 511.5f);
        float t00 = fmaf(xf0, c, b0);
        float t10 = fmaf(xf0 + (float)(BX - 1), c, b0);
        float t01 = fmaf(xf0, c, b1);
        float t11 = fmaf(xf0 + (float)(BX - 1), c, b1);
        imintab[v] = (int)fminf(fminf(t00, t10), fminf(t01, t11));
    }
    __syncthreads();

    const int x = blockIdx.x * BX + threadIdx.x;
    const int y = blockIdx.y * BY + threadIdx.y;
    const float xf = (float)x - 255.5f;
    const float yf = (float)y - 255.5f;

    float acc[ZG];
    #pragma unroll
    for (int z = 0; z < ZG; ++z) acc[z] = 0.0f;

    // Staging: NR rows x 16 dw = 96 x4-chunks, spread over all 4 waves
    // (24 lanes per wave) so barrier arrival stays balanced.
    const int  wv   = tid >> 6;
    const int  ln   = tid & 63;
    const bool sact = (ln < 24);
    const int  slot = wv * 24 + ln;          // 0..95
    const int  sr   = slot >> 2;             // staged row 0..23
    const int  sch  = slot & 3;              // 16B chunk 0..3 (unswizzled)
    const size_t sg_off = ((size_t)sr << 5) + (g << 4) + (sch << 2);   // global dw off
    const int  swr  = sr * RSTRIDE + (sch << 2);                        // LDS dw off

    uint4 st;
    if (sact) {  // prologue: stage view 0 into buffer 0
        st = *(const uint4*)(packed + ((size_t)imintab[0] << 5) + sg_off);
        *(uint4*)&stage[0][swr] = st;
    }
    __syncthreads();

    #pragma unroll 2
    for (int v = 0; v < NVIEW; ++v) {
        // [A] prefetch staging for v+1 (consumed at [F]; ~1 view of flight time)
        if (sact && v + 1 < NVIEW) {
            st = *(const uint4*)(packed + ((size_t)(v + 1) << 15)
                                 + ((size_t)imintab[v + 1] << 5) + sg_off);
        }

        float2 a = cs[v];
        float t  = fmaf(xf, a.x, fmaf(yf, a.y, 511.5f));
        int   i0 = (int)t;                       // t in [150,873] -> trunc == floor
        float w  = t - (float)i0;
        int   rl = i0 - imintab[v];              // in [0, NR) -- bound is exact

#if USE_FDOT2
        half2v wpair;
        wpair[0] = (_Float16)1.0f;
        wpair[1] = (_Float16)w;
#endif

        // [C] LDS gather: 4x b128 off one base address (imm offsets 0/64/128/192 B)
        const uint* sp = stage[v & 1] + rl * RSTRIDE;
        uint4 q0 = *(const uint4*)(sp);
        uint4 q1 = *(const uint4*)(sp + 4);
        uint4 q2 = *(const uint4*)(sp + 8);
        uint4 q3 = *(const uint4*)(sp + 12);

        SAMPLE( 0, q0.x); SAMPLE( 1, q0.y); SAMPLE( 2, q0.z); SAMPLE( 3, q0.w);
        SAMPLE( 4, q1.x); SAMPLE( 5, q1.y); SAMPLE( 6, q1.z); SAMPLE( 7, q1.w);
        SAMPLE( 8, q2.x); SAMPLE( 9, q2.y); SAMPLE(10, q2.z); SAMPLE(11, q2.w);
        SAMPLE(12, q3.x); SAMPLE(13, q3.y); SAMPLE(14, q3.z); SAMPLE(15, q3.w);

        // [F] publish view v+1 stage (vmcnt waits only on st, issued at [A])
        if (sact && v + 1 < NVIEW) *(uint4*)&stage[(v + 1) & 1][swr] = st;
        // [G] one barrier per view (orders iter-(v+1) writes of a buffer after
        // all iter-v reads of it -> race-free double buffer)
        __syncthreads();
    }

    const float scale = 0.0043633231299858236f;  // pi / 720
    #pragma unroll
    for (int lz = 0; lz < ZG; ++lz) {
        out[(((size_t)(g * ZG + lz)) * NY + y) * NX + x] = acc[lz] * scale;
    }
}

// Fallback (ws too small for packed array): direct fp32, two loads per sample.
__global__ __launch_bounds__(256) void bp_direct(const float* __restrict__ xin,
                                                 float* __restrict__ out) {
    __shared__ float2 cs[NVIEW];
    int lt = threadIdx.y * 64 + threadIdx.x;
    for (int v = lt; v < NVIEW; v += 256) {
        float th = (float)v * (float)(M_PI / NVIEW);
        float s, c;
        sincosf(th, &s, &c);
        cs[v] = make_float2(c, s);
    }
    __syncthreads();

    int x = blockIdx.x * 64 + threadIdx.x;
    int y = blockIdx.y * 4 + threadIdx.y;
    float xf = (float)x - 255.5f;
    float yf = (float)y - 255.5f;

    float acc[NZ];
    #pragma unroll
    for (int z = 0; z < NZ; ++z) acc[z] = 0.0f;

    for (int v = 0; v < NVIEW; ++v) {
        float2 a = cs[v];
        float t  = fmaf(xf, a.x, fmaf(yf, a.y, 511.5f));
        int   i0 = (int)t;
        float w  = t - (float)i0;
        const float* p = xin + (size_t)v * NDCT + i0;
        #pragma unroll
        for (int z = 0; z < NZ; ++z) {
            float g0 = p[(size_t)z * NVIEW * NDCT];
            float g1 = p[(size_t)z * NVIEW * NDCT + 1];
            acc[z] += fmaf(w, g1 - g0, g0);
        }
    }

    const float scale = 0.0043633231299858236f;
    #pragma unroll
    for (int z = 0; z < NZ; ++z) {
        out[((size_t)z * NY + y) * NX + x] = acc[z] * scale;
    }
}

extern "C" void kernel_launch(void* const* d_in, const int* in_sizes, int n_in,
                              void* d_out, int out_size, void* d_ws, size_t ws_size,
                              hipStream_t stream) {
    const float* x = (const float*)d_in[0];
    float* out = (float*)d_out;

    const size_t packed_bytes = (size_t)NVIEW * NDCT * NZ * sizeof(uint);  // 94.4 MB

    if (ws_size >= packed_bytes) {
        uint* packed = (uint*)d_ws;
        pack_kernel<<<dim3(NVIEW, NDCT / 64), 64, 0, stream>>>(x, packed);
        bp_lds<<<dim3(NX / BX, NY / BY, 2), dim3(BX, BY), 0, stream>>>(packed, out);
    } else {
        bp_direct<<<dim3(NX / 64, NY / 4), dim3(64, 4), 0, stream>>>(x, out);
    }
}